// Round 1
// baseline (220.837 us; speedup 1.0000x reference)
//
#include <hip/hip_runtime.h>

#define N 8192
#define IN_DIM 128
#define LD 32
#define NE 100000.0f

// ---------------- Kernel A: column softmax (axis=0) of the 3 transforms ----
__global__ __launch_bounds__(64) void softmax_cols_k(
        const float* __restrict__ tz, const float* __restrict__ tg,
        const float* __restrict__ td, float* __restrict__ ws_t) {
    int b = blockIdx.x;
    const float* src = (b == 0) ? tz : (b == 1) ? tg : td;
    float* dst = ws_t + b * (IN_DIM * LD);
    int d = threadIdx.x;
    if (d >= LD) return;
    float mx = -1e30f;
    for (int k = 0; k < IN_DIM; ++k) mx = fmaxf(mx, src[k * LD + d]);
    float s = 0.0f;
    for (int k = 0; k < IN_DIM; ++k) s += expf(src[k * LD + d] - mx);
    float inv = 1.0f / s;
    for (int k = 0; k < IN_DIM; ++k) dst[k * LD + d] = expf(src[k * LD + d] - mx) * inv;
}

// ---------------- Kernel B: 4 decode GEMMs + per-row constant c[i] ---------
#define ROWS_B 8
__global__ __launch_bounds__(256) void decode_k(
        const float* __restrict__ z1, const float* __restrict__ gamma,
        const float* __restrict__ z2, const float* __restrict__ delta,
        const float* __restrict__ ws_t,
        const float* __restrict__ p_bias, const float* __restrict__ p_wg,
        const float* __restrict__ p_wd,
        float* __restrict__ dec_out,   // d_out + N*N: z_dec1|z_dec2|gam|del
        float* __restrict__ ws_c) {
    __shared__ float sZ[4][ROWS_B][IN_DIM];   // 16 KB
    int t = threadIdx.x;
    int row0 = blockIdx.x * ROWS_B;
    for (int i = t; i < 4 * ROWS_B * IN_DIM; i += 256) {
        int a = i >> 10;
        int rr = (i >> 7) & (ROWS_B - 1);
        int k = i & (IN_DIM - 1);
        const float* src = (a == 0) ? z1 : (a == 1) ? z2 : (a == 2) ? gamma : delta;
        (&sZ[0][0][0])[i] = src[(long long)(row0 + rr) * IN_DIM + k];
    }
    __syncthreads();
    int d = t & 31, r = t >> 5;
    const float* tzp = ws_t;
    const float* tgp = ws_t + IN_DIM * LD;
    const float* tdp = ws_t + 2 * IN_DIM * LD;
    float a1 = 0.f, a2 = 0.f, ag = 0.f, ad = 0.f;
    #pragma unroll 8
    for (int k = 0; k < IN_DIM; ++k) {
        float tzv = tzp[k * LD + d];
        float tgv = tgp[k * LD + d];
        float tdv = tdp[k * LD + d];
        a1 += sZ[0][r][k] * tzv;
        a2 += sZ[1][r][k] * tzv;
        ag += sZ[2][r][k] * tgv;
        ad += sZ[3][r][k] * tdv;
    }
    long long i = row0 + r;
    dec_out[i * LD + d] = a1;
    dec_out[(long long)N * LD + i * LD + d] = a2;
    dec_out[2LL * N * LD + i * LD + d] = ag;
    dec_out[3LL * N * LD + i * LD + d] = ad;
    float wg = p_wg[0], wd = p_wd[0];
    float w = wg * (ag + 1e-16f) + wd * (ad + 1e-16f);
    float ct = w * a1 * a1;
    ct += __shfl_xor(ct, 1);
    ct += __shfl_xor(ct, 2);
    ct += __shfl_xor(ct, 4);
    ct += __shfl_xor(ct, 8);
    ct += __shfl_xor(ct, 16);
    if (d == 0) ws_c[i] = p_bias[0] - NE * ct;
}

// ---------------- Kernel C: rank-64 distance GEMM + sigmoid ----------------
#define BM 128
#define BN 128
#define PAD 132
__global__ __launch_bounds__(256) void dist_sigmoid_k(
        const float* __restrict__ dec,    // d_out + N*N
        const float* __restrict__ ws_c,
        const float* __restrict__ p_wg, const float* __restrict__ p_wd,
        float* __restrict__ out) {
    __align__(16) __shared__ float sP[LD][PAD];
    __align__(16) __shared__ float sQ[LD][PAD];
    __align__(16) __shared__ float sY[LD][PAD];
    const float* zd1 = dec;
    const float* zd2 = dec + (long long)N * LD;
    const float* gam = dec + 2LL * N * LD;
    const float* del = dec + 3LL * N * LD;
    int t = threadIdx.x;
    int row0 = blockIdx.y * BM;
    int col0 = blockIdx.x * BN;
    float wg = p_wg[0], wd = p_wd[0];
    // stage P, Q (d-major)
    for (int i = t; i < BM * LD; i += 256) {
        int m = i >> 5, d = i & 31;
        float x = zd1[(long long)row0 * LD + i];
        float w = wg * (gam[(long long)row0 * LD + i] + 1e-16f)
                + wd * (del[(long long)row0 * LD + i] + 1e-16f);
        sP[d][m] = (2.0f * NE) * w * x;
        sQ[d][m] = -NE * w;
    }
    // stage Y (d-major); Y^2 computed in-register in the main loop
    for (int i = t; i < BN * LD; i += 256) {
        int n = i >> 5, d = i & 31;
        sY[d][n] = zd2[(long long)col0 * LD + i];
    }
    __syncthreads();

    int tc = t & 15, tr = t >> 4;     // 16x16 thread grid
    int r0 = tr * 8, c0 = tc * 8;     // 8x8 outputs per thread
    float acc[8][8];
    #pragma unroll
    for (int m = 0; m < 8; ++m) {
        float cv = ws_c[row0 + r0 + m];
        #pragma unroll
        for (int n = 0; n < 8; ++n) acc[m][n] = cv;
    }
    #pragma unroll
    for (int d = 0; d < LD; ++d) {
        float4 p0 = *(const float4*)&sP[d][r0];
        float4 p1 = *(const float4*)&sP[d][r0 + 4];
        float4 q0 = *(const float4*)&sQ[d][r0];
        float4 q1 = *(const float4*)&sQ[d][r0 + 4];
        float4 y0 = *(const float4*)&sY[d][c0];
        float4 y1 = *(const float4*)&sY[d][c0 + 4];
        float pm[8] = {p0.x,p0.y,p0.z,p0.w,p1.x,p1.y,p1.z,p1.w};
        float qm[8] = {q0.x,q0.y,q0.z,q0.w,q1.x,q1.y,q1.z,q1.w};
        float yn[8] = {y0.x,y0.y,y0.z,y0.w,y1.x,y1.y,y1.z,y1.w};
        float vn[8];
        #pragma unroll
        for (int n = 0; n < 8; ++n) vn[n] = yn[n] * yn[n];
        #pragma unroll
        for (int m = 0; m < 8; ++m)
            #pragma unroll
            for (int n = 0; n < 8; ++n)
                acc[m][n] += pm[m] * yn[n] + qm[m] * vn[n];
    }
    #pragma unroll
    for (int m = 0; m < 8; ++m) {
        float res[8];
        #pragma unroll
        for (int n = 0; n < 8; ++n) {
            float e = __expf(-acc[m][n]);
            res[n] = __builtin_amdgcn_rcpf(1.0f + e);
        }
        long long base = (long long)(row0 + r0 + m) * N + col0 + c0;
        *(float4*)&out[base]     = make_float4(res[0], res[1], res[2], res[3]);
        *(float4*)&out[base + 4] = make_float4(res[4], res[5], res[6], res[7]);
    }
}

extern "C" void kernel_launch(void* const* d_in, const int* in_sizes, int n_in,
                              void* d_out, int out_size, void* d_ws, size_t ws_size,
                              hipStream_t stream) {
    const float* z1    = (const float*)d_in[0];
    const float* gamma = (const float*)d_in[1];
    const float* z2    = (const float*)d_in[2];
    const float* delta = (const float*)d_in[3];
    const float* tz    = (const float*)d_in[4];
    const float* tg    = (const float*)d_in[5];
    const float* td    = (const float*)d_in[6];
    const float* bias  = (const float*)d_in[7];
    const float* wgp   = (const float*)d_in[8];
    const float* wdp   = (const float*)d_in[9];
    float* out = (float*)d_out;
    float* dec_out = out + (long long)N * N;       // z_dec1|z_dec2|gam_dec|del_dec
    float* ws_t = (float*)d_ws;                    // 3*128*32 floats (48 KB)
    float* ws_c = ws_t + 3 * IN_DIM * LD;          // N floats (32 KB)

    softmax_cols_k<<<dim3(3), dim3(64), 0, stream>>>(tz, tg, td, ws_t);
    decode_k<<<dim3(N / ROWS_B), dim3(256), 0, stream>>>(
        z1, gamma, z2, delta, ws_t, bias, wgp, wdp, dec_out, ws_c);
    dist_sigmoid_k<<<dim3(N / BN, N / BM), dim3(256), 0, stream>>>(
        dec_out, ws_c, wgp, wdp, out);
}

// Round 3
// 203.127 us; speedup vs baseline: 1.0872x; 1.0872x over previous
//
#include <hip/hip_runtime.h>

#define N 8192
#define IN_DIM 128
#define LD 32
#define NE 100000.0f

typedef float v4f __attribute__((ext_vector_type(4)));

// ---------------- Kernel A: column softmax (axis=0) of the 3 transforms ----
// 3 blocks x 256 threads; 8 threads per column, shfl-reduced.
__global__ __launch_bounds__(256) void softmax_cols_k(
        const float* __restrict__ tz, const float* __restrict__ tg,
        const float* __restrict__ td, float* __restrict__ ws_t) {
    int b = blockIdx.x;
    const float* src = (b == 0) ? tz : (b == 1) ? tg : td;
    float* dst = ws_t + b * (IN_DIM * LD);
    int col = threadIdx.x >> 3, sub = threadIdx.x & 7;   // 32 cols x 8 subs
    float mx = -1e30f;
    #pragma unroll
    for (int j = 0; j < 16; ++j) mx = fmaxf(mx, src[(sub + 8 * j) * LD + col]);
    mx = fmaxf(mx, __shfl_xor(mx, 1));
    mx = fmaxf(mx, __shfl_xor(mx, 2));
    mx = fmaxf(mx, __shfl_xor(mx, 4));
    float s = 0.0f;
    #pragma unroll
    for (int j = 0; j < 16; ++j) s += __expf(src[(sub + 8 * j) * LD + col] - mx);
    s += __shfl_xor(s, 1);
    s += __shfl_xor(s, 2);
    s += __shfl_xor(s, 4);
    float inv = 1.0f / s;
    #pragma unroll
    for (int j = 0; j < 16; ++j)
        dst[(sub + 8 * j) * LD + col] = __expf(src[(sub + 8 * j) * LD + col] - mx) * inv;
}

// ---------------- Kernel B: 4 decode GEMMs + per-row constant c[i] ---------
#define ROWS_B 8
__global__ __launch_bounds__(256) void decode_k(
        const float* __restrict__ z1, const float* __restrict__ gamma,
        const float* __restrict__ z2, const float* __restrict__ delta,
        const float* __restrict__ ws_t,
        const float* __restrict__ p_bias, const float* __restrict__ p_wg,
        const float* __restrict__ p_wd,
        float* __restrict__ dec_out,   // d_out + N*N: z_dec1|z_dec2|gam|del
        float* __restrict__ ws_c) {
    __shared__ float sZ[4][ROWS_B][IN_DIM];   // 16 KB
    int t = threadIdx.x;
    int row0 = blockIdx.x * ROWS_B;
    for (int i = t; i < 4 * ROWS_B * IN_DIM; i += 256) {
        int a = i >> 10;
        int rr = (i >> 7) & (ROWS_B - 1);
        int k = i & (IN_DIM - 1);
        const float* src = (a == 0) ? z1 : (a == 1) ? z2 : (a == 2) ? gamma : delta;
        (&sZ[0][0][0])[i] = src[(long long)(row0 + rr) * IN_DIM + k];
    }
    __syncthreads();
    int d = t & 31, r = t >> 5;
    const float* tzp = ws_t;
    const float* tgp = ws_t + IN_DIM * LD;
    const float* tdp = ws_t + 2 * IN_DIM * LD;
    float a1 = 0.f, a2 = 0.f, ag = 0.f, ad = 0.f;
    #pragma unroll 8
    for (int k = 0; k < IN_DIM; ++k) {
        float tzv = tzp[k * LD + d];
        float tgv = tgp[k * LD + d];
        float tdv = tdp[k * LD + d];
        a1 += sZ[0][r][k] * tzv;
        a2 += sZ[1][r][k] * tzv;
        ag += sZ[2][r][k] * tgv;
        ad += sZ[3][r][k] * tdv;
    }
    long long i = row0 + r;
    dec_out[i * LD + d] = a1;
    dec_out[(long long)N * LD + i * LD + d] = a2;
    dec_out[2LL * N * LD + i * LD + d] = ag;
    dec_out[3LL * N * LD + i * LD + d] = ad;
    float wg = p_wg[0], wd = p_wd[0];
    float w = wg * (ag + 1e-16f) + wd * (ad + 1e-16f);
    float ct = w * a1 * a1;
    ct += __shfl_xor(ct, 1);
    ct += __shfl_xor(ct, 2);
    ct += __shfl_xor(ct, 4);
    ct += __shfl_xor(ct, 8);
    ct += __shfl_xor(ct, 16);
    if (d == 0) ws_c[i] = p_bias[0] - NE * ct;
}

// ---------------- Kernel C: rank-64 distance GEMM + sigmoid ----------------
// logit[i,j] = c[i] + sum_d P[d,i]*y[d,j] + Q[d,i]*y[d,j]^2
// LDS layout: 3 arrays [32][128] f32, 512B row stride, 16B-chunk XOR swizzle
// (chunk g -> g ^ (g>>3)) so Y-reads are 2-way (free) instead of 4-way.
#define BM 128
#define BN 128

__device__ __forceinline__ int swz_byte(int d, int c) {
    int g = c >> 2;
    int gs = g ^ (g >> 3);
    return (d << 9) + (gs << 4) + ((c & 3) << 2);
}

__global__ __launch_bounds__(256, 2) void dist_sigmoid_k(
        const float* __restrict__ dec,    // d_out + N*N
        const float* __restrict__ ws_c,
        const float* __restrict__ p_wg, const float* __restrict__ p_wd,
        float* __restrict__ out) {
    __shared__ float lds[3 * LD * BM];     // P | Q | Y, 48 KB
    char* ldsb = (char*)lds;
    const float* zd1 = dec;
    const float* zd2 = dec + (long long)N * LD;
    const float* gam = dec + 2LL * N * LD;
    const float* del = dec + 3LL * N * LD;
    int t = threadIdx.x;
    int row0 = blockIdx.y * BM;
    int col0 = blockIdx.x * BN;
    float wg = p_wg[0], wd = p_wd[0];

    // stage P, Q, Y (d-major, swizzled). c-fastest => conflict-free LDS writes.
    for (int i = t; i < LD * BM; i += 256) {
        int d = i >> 7, c = i & 127;
        int ob = swz_byte(d, c);
        long long ri = (long long)(row0 + c) * LD + d;
        long long ci = (long long)(col0 + c) * LD + d;
        float x = zd1[ri];
        float w = wg * (gam[ri] + 1e-16f) + wd * (del[ri] + 1e-16f);
        *(float*)(ldsb + ob)         = (2.0f * NE) * w * x;   // P
        *(float*)(ldsb + 16384 + ob) = -NE * w;               // Q
        *(float*)(ldsb + 32768 + ob) = zd2[ci];               // Y
    }
    __syncthreads();

    int tc = t & 15, tr = t >> 4;     // 16x16 thread grid
    int r0 = tr * 8, c0 = tc * 8;     // 8x8 outputs per thread

    // swizzled base pointers (chunk indices 2*tr, 2*tr+1 / 2*tc, 2*tc+1)
    int gr0 = 2 * tr, gr1 = 2 * tr + 1;
    int gc0 = 2 * tc, gc1 = 2 * tc + 1;
    const char* pP0 = ldsb + ((gr0 ^ (gr0 >> 3)) << 4);
    const char* pP1 = ldsb + ((gr1 ^ (gr1 >> 3)) << 4);
    const char* pQ0 = pP0 + 16384;
    const char* pQ1 = pP1 + 16384;
    const char* pY0 = ldsb + 32768 + ((gc0 ^ (gc0 >> 3)) << 4);
    const char* pY1 = ldsb + 32768 + ((gc1 ^ (gc1 >> 3)) << 4);

    float acc[8][8];
    #pragma unroll
    for (int m = 0; m < 8; ++m) {
        float cv = ws_c[row0 + r0 + m];
        #pragma unroll
        for (int n = 0; n < 8; ++n) acc[m][n] = cv;
    }

    #pragma unroll 4
    for (int d = 0; d < LD; ++d) {
        float4 P0 = *(const float4*)(pP0 + (d << 9));
        float4 P1 = *(const float4*)(pP1 + (d << 9));
        float4 Q0 = *(const float4*)(pQ0 + (d << 9));
        float4 Q1 = *(const float4*)(pQ1 + (d << 9));
        float4 Y0 = *(const float4*)(pY0 + (d << 9));
        float4 Y1 = *(const float4*)(pY1 + (d << 9));
        float pm[8] = {P0.x,P0.y,P0.z,P0.w,P1.x,P1.y,P1.z,P1.w};
        float qm[8] = {Q0.x,Q0.y,Q0.z,Q0.w,Q1.x,Q1.y,Q1.z,Q1.w};
        float yn[8] = {Y0.x,Y0.y,Y0.z,Y0.w,Y1.x,Y1.y,Y1.z,Y1.w};
        #pragma unroll
        for (int m = 0; m < 8; ++m) {
            #pragma unroll
            for (int n = 0; n < 8; ++n) {
                float tmp = __builtin_fmaf(qm[m], yn[n], pm[m]);
                acc[m][n] = __builtin_fmaf(tmp, yn[n], acc[m][n]);
            }
        }
    }

    #pragma unroll
    for (int m = 0; m < 8; ++m) {
        float res[8];
        #pragma unroll
        for (int n = 0; n < 8; ++n) {
            float e = __expf(-acc[m][n]);
            res[n] = __builtin_amdgcn_rcpf(1.0f + e);
        }
        long long base = (long long)(row0 + r0 + m) * N + col0 + c0;
        v4f lo = {res[0], res[1], res[2], res[3]};
        v4f hi = {res[4], res[5], res[6], res[7]};
        __builtin_nontemporal_store(lo, (v4f*)&out[base]);
        __builtin_nontemporal_store(hi, (v4f*)&out[base + 4]);
    }
}

extern "C" void kernel_launch(void* const* d_in, const int* in_sizes, int n_in,
                              void* d_out, int out_size, void* d_ws, size_t ws_size,
                              hipStream_t stream) {
    const float* z1    = (const float*)d_in[0];
    const float* gamma = (const float*)d_in[1];
    const float* z2    = (const float*)d_in[2];
    const float* delta = (const float*)d_in[3];
    const float* tz    = (const float*)d_in[4];
    const float* tg    = (const float*)d_in[5];
    const float* td    = (const float*)d_in[6];
    const float* bias  = (const float*)d_in[7];
    const float* wgp   = (const float*)d_in[8];
    const float* wdp   = (const float*)d_in[9];
    float* out = (float*)d_out;
    float* dec_out = out + (long long)N * N;       // z_dec1|z_dec2|gam_dec|del_dec
    float* ws_t = (float*)d_ws;                    // 3*128*32 floats (48 KB)
    float* ws_c = ws_t + 3 * IN_DIM * LD;          // N floats (32 KB)

    softmax_cols_k<<<dim3(3), dim3(256), 0, stream>>>(tz, tg, td, ws_t);
    decode_k<<<dim3(N / ROWS_B), dim3(256), 0, stream>>>(
        z1, gamma, z2, delta, ws_t, bias, wgp, wdp, dec_out, ws_c);
    dist_sigmoid_k<<<dim3(N / BN, N / BM), dim3(256), 0, stream>>>(
        dec_out, ws_c, wgp, wdp, out);
}